// Round 1
// baseline (1193.475 us; speedup 1.0000x reference)
//
#include <hip/hip_runtime.h>
#include <cstdint>
#include <cstddef>

// Problem dims (RNN_57208964382771)
#define Bz 64
#define Tz 2048
#define Hz 8
#define Vz 1000
#define Oz 1000

// ---------------------------------------------------------------------------
// Kernel 1: x_proj[b,t,i] = dot(emb[X[b,t]], W_ih[i,:]) + b_ih[i]
// Also writes the lengths tail of d_out (output 1 of the tuple, as float).
// ---------------------------------------------------------------------------
__global__ __launch_bounds__(256) void k_xproj(
    const int* __restrict__ X, const int* __restrict__ lengths,
    const float* __restrict__ emb, const float* __restrict__ W_ih,
    const float* __restrict__ b_ih, float* __restrict__ xproj,
    float* __restrict__ out_tail)
{
    int r = blockIdx.x * 256 + threadIdx.x;
    if (r < Bz * Tz) {
        int v = X[r];
        const float4* e4 = (const float4*)(emb + (size_t)v * Hz);
        float4 ea = e4[0], eb = e4[1];
        float res[8];
#pragma unroll
        for (int i = 0; i < 8; ++i) {
            const float* w = W_ih + i * 8;  // uniform address -> scalar loads
            float a = b_ih[i];
            a = fmaf(ea.x, w[0], a); a = fmaf(ea.y, w[1], a);
            a = fmaf(ea.z, w[2], a); a = fmaf(ea.w, w[3], a);
            a = fmaf(eb.x, w[4], a); a = fmaf(eb.y, w[5], a);
            a = fmaf(eb.z, w[6], a); a = fmaf(eb.w, w[7], a);
            res[i] = a;
        }
        float4* o4 = (float4*)(xproj + (size_t)r * 8);
        o4[0] = make_float4(res[0], res[1], res[2], res[3]);
        o4[1] = make_float4(res[4], res[5], res[6], res[7]);
    }
    if (r < Bz) out_tail[r] = (float)lengths[r];
}

// ---------------------------------------------------------------------------
// Kernel 2: sequential scan  h = tanh(x_proj_t + W_hh h + b_hh)
// 4 lanes per batch; lane q holds h[2q], h[2q+1]. Cross-lane h all-gather via
// DPP quad_perm rotations (no LDS round trip -> short dependency chain).
// Stores hs masked (0 for t >= length).
// ---------------------------------------------------------------------------
#define QROT(x, CTRL) \
    __int_as_float(__builtin_amdgcn_update_dpp(0, __float_as_int(x), (CTRL), 0xF, 0xF, true))
// quad_perm ctrl: rot1=[1,2,3,0]=0x39, rot2=[2,3,0,1]=0x4E, rot3=[3,0,1,2]=0x93

__device__ __forceinline__ float fast_tanh(float x) {
    x = fminf(15.0f, fmaxf(-15.0f, x));
    float e = __expf(2.0f * x);            // v_exp_f32
    return __fdividef(e - 1.0f, e + 1.0f); // v_rcp_f32 path
}

__global__ __launch_bounds__(64) void k_scan(
    const float* __restrict__ xproj, const int* __restrict__ lengths,
    const float* __restrict__ W_hh, const float* __restrict__ b_hh,
    float* __restrict__ hs)
{
    int lane = threadIdx.x;                 // 0..63, one wave
    int b = blockIdx.x * 16 + (lane >> 2);  // 16 batches per wave
    int q = lane & 3;
    int i0 = 2 * q, i1 = 2 * q + 1;

    // Weights in quad-rotation order: term r uses h-pair from lane (q+r)&3.
    float w0[8], w1[8];
#pragma unroll
    for (int r = 0; r < 4; ++r) {
        int jj = ((q + r) & 3) * 2;
        w0[2 * r]     = W_hh[i0 * 8 + jj];
        w0[2 * r + 1] = W_hh[i0 * 8 + jj + 1];
        w1[2 * r]     = W_hh[i1 * 8 + jj];
        w1[2 * r + 1] = W_hh[i1 * 8 + jj + 1];
    }
    float bh0 = b_hh[i0], bh1 = b_hh[i1];
    int len = lengths[b];
    const float* xp_base = xproj + (size_t)b * Tz * 8 + 2 * q;
    float* hs_base = hs + (size_t)b * Tz * 8 + 2 * q;

    float h0 = 0.0f, h1 = 0.0f;
    for (int t = 0; t < Tz; ++t) {
        float2 xp = *(const float2*)(xp_base + (size_t)t * 8); // off critical path
        // gather the other 3 h-pairs of this batch's quad
        float p1x = QROT(h0, 0x39), p1y = QROT(h1, 0x39);
        float p2x = QROT(h0, 0x4E), p2y = QROT(h1, 0x4E);
        float p3x = QROT(h0, 0x93), p3y = QROT(h1, 0x93);

        float a0 = bh0 + xp.x;
        float a1 = bh1 + xp.y;
        a0 = fmaf(h0,  w0[0], a0); a0 = fmaf(h1,  w0[1], a0);
        a0 = fmaf(p1x, w0[2], a0); a0 = fmaf(p1y, w0[3], a0);
        a0 = fmaf(p2x, w0[4], a0); a0 = fmaf(p2y, w0[5], a0);
        a0 = fmaf(p3x, w0[6], a0); a0 = fmaf(p3y, w0[7], a0);
        a1 = fmaf(h0,  w1[0], a1); a1 = fmaf(h1,  w1[1], a1);
        a1 = fmaf(p1x, w1[2], a1); a1 = fmaf(p1y, w1[3], a1);
        a1 = fmaf(p2x, w1[4], a1); a1 = fmaf(p2y, w1[5], a1);
        a1 = fmaf(p3x, w1[6], a1); a1 = fmaf(p3y, w1[7], a1);

        h0 = fast_tanh(a0);
        h1 = fast_tanh(a1);

        float2 hv;
        hv.x = (t < len) ? h0 : 0.0f;
        hv.y = (t < len) ? h1 : 0.0f;
        *(float2*)(hs_base + (size_t)t * 8) = hv;  // off critical path
    }
}

// ---------------------------------------------------------------------------
// Kernel 3: logits[r, o] = sum_i hs[r,i] * W_out[o,i] + b_out[o]
// r = b*T + t (131072 rows). Memory-bound on the 524 MB logits write.
// Each block: 128 rows staged in LDS; each thread owns 4 output columns with
// W_out coefficients held in VGPRs; one float4 store per row per thread.
// ---------------------------------------------------------------------------
__global__ __launch_bounds__(256) void k_out(
    const float* __restrict__ hs, const float* __restrict__ W_out,
    const float* __restrict__ b_out, float* __restrict__ out)
{
    __shared__ float sh[128 * 8];  // 4 KB
    int tid = threadIdx.x;
    int r0 = blockIdx.x * 128;

    // cooperative stage of 128 hs rows (contiguous 4 KB)
    ((float4*)sh)[tid] = ((const float4*)(hs + (size_t)r0 * 8))[tid];
    __syncthreads();

    if (tid >= Oz / 4) return;  // 250 active threads

    float w[4][8];
    float bo[4];
#pragma unroll
    for (int k = 0; k < 4; ++k) {
        const float4* wr = (const float4*)(W_out + (size_t)(tid * 4 + k) * 8);
        float4 wa = wr[0], wb = wr[1];
        w[k][0] = wa.x; w[k][1] = wa.y; w[k][2] = wa.z; w[k][3] = wa.w;
        w[k][4] = wb.x; w[k][5] = wb.y; w[k][6] = wb.z; w[k][7] = wb.w;
        bo[k] = b_out[tid * 4 + k];
    }

    for (int rr = 0; rr < 128; ++rr) {
        const float4* s4 = (const float4*)(sh + rr * 8);
        float4 ha = s4[0], hb = s4[1];  // LDS broadcast reads
        float4 acc;
        float* ap = &acc.x;
#pragma unroll
        for (int k = 0; k < 4; ++k) {
            float a = bo[k];
            a = fmaf(ha.x, w[k][0], a); a = fmaf(ha.y, w[k][1], a);
            a = fmaf(ha.z, w[k][2], a); a = fmaf(ha.w, w[k][3], a);
            a = fmaf(hb.x, w[k][4], a); a = fmaf(hb.y, w[k][5], a);
            a = fmaf(hb.z, w[k][6], a); a = fmaf(hb.w, w[k][7], a);
            ap[k] = a;
        }
        ((float4*)(out + (size_t)(r0 + rr) * Oz))[tid] = acc;
    }
}

// ---------------------------------------------------------------------------
extern "C" void kernel_launch(void* const* d_in, const int* in_sizes, int n_in,
                              void* d_out, int out_size, void* d_ws, size_t ws_size,
                              hipStream_t stream)
{
    const int*   X       = (const int*)d_in[0];
    const int*   lengths = (const int*)d_in[1];
    const float* emb     = (const float*)d_in[2];
    const float* W_ih    = (const float*)d_in[3];
    const float* W_hh    = (const float*)d_in[4];
    const float* b_ih    = (const float*)d_in[5];
    const float* b_hh    = (const float*)d_in[6];
    const float* W_out   = (const float*)d_in[7];
    const float* b_out   = (const float*)d_in[8];

    float* out   = (float*)d_out;
    float* xproj = (float*)d_ws;                       // 4 MB
    float* hs    = xproj + (size_t)Bz * Tz * Hz;       // 4 MB (needs ws >= 8 MB)

    // lengths tail of d_out (output 1 of the tuple)
    float* out_tail = out + (size_t)Bz * Tz * Oz;

    k_xproj<<<(Bz * Tz + 255) / 256, 256, 0, stream>>>(X, lengths, emb, W_ih, b_ih,
                                                       xproj, out_tail);
    k_scan<<<Bz / 16, 64, 0, stream>>>(xproj, lengths, W_hh, b_hh, hs);
    k_out<<<(Bz * Tz) / 128, 256, 0, stream>>>(hs, W_out, b_out, out);
}

// Round 2
// 752.985 us; speedup vs baseline: 1.5850x; 1.5850x over previous
//
#include <hip/hip_runtime.h>
#include <cstdint>
#include <cstddef>

// Problem dims (RNN_57208964382771)
#define Bz 64
#define Tz 2048
#define Hz 8
#define Vz 1000
#define Oz 1000

typedef float f32x4 __attribute__((ext_vector_type(4)));

// ---------------------------------------------------------------------------
// Kernel 1: xpT[b][q][t][e] = dot(emb[X[b,t]], W_ih[2q+e,:]) + b_ih + b_hh
// Lane-major layout so the scan's per-lane reads are contiguous over t.
// Also writes the lengths tail of d_out (output 1 of the tuple, as float).
// ---------------------------------------------------------------------------
__global__ __launch_bounds__(256) void k_xproj(
    const int* __restrict__ X, const int* __restrict__ lengths,
    const float* __restrict__ emb, const float* __restrict__ W_ih,
    const float* __restrict__ b_ih, const float* __restrict__ b_hh,
    float* __restrict__ xpT, float* __restrict__ out_tail)
{
    int r = blockIdx.x * 256 + threadIdx.x;
    if (r < Bz * Tz) {
        int v = X[r];
        const float4* e4 = (const float4*)(emb + (size_t)v * Hz);
        float4 ea = e4[0], eb = e4[1];
        float res[8];
#pragma unroll
        for (int i = 0; i < 8; ++i) {
            const float* w = W_ih + i * 8;  // uniform address -> scalar loads
            float a = b_ih[i] + b_hh[i];
            a = fmaf(ea.x, w[0], a); a = fmaf(ea.y, w[1], a);
            a = fmaf(ea.z, w[2], a); a = fmaf(ea.w, w[3], a);
            a = fmaf(eb.x, w[4], a); a = fmaf(eb.y, w[5], a);
            a = fmaf(eb.z, w[6], a); a = fmaf(eb.w, w[7], a);
            res[i] = a;
        }
        int b = r >> 11, t = r & 2047;
#pragma unroll
        for (int q = 0; q < 4; ++q) {
            *(float2*)(xpT + ((size_t)(b * 4 + q) * Tz + t) * 2) =
                make_float2(res[2 * q], res[2 * q + 1]);
        }
    }
    if (r < Bz) out_tail[r] = (float)lengths[r];
}

// ---------------------------------------------------------------------------
// Kernel 2: sequential scan  h = tanh(xp_t + W_hh h)   (biases folded into xp)
// 4 lanes per batch; lane q holds h[2q], h[2q+1]. Cross-lane h all-gather via
// DPP quad_perm rotations. Software-pipelined: prefetch next 8 steps' xp
// (4 x float4, contiguous) while computing the current 8 steps.
// hs stored UNMASKED; k_out applies the length mask during staging.
// ---------------------------------------------------------------------------
#define QROT(x, CTRL) \
    __int_as_float(__builtin_amdgcn_update_dpp(0, __float_as_int(x), (CTRL), 0xF, 0xF, true))
// quad_perm ctrl: rot1=[1,2,3,0]=0x39, rot2=[2,3,0,1]=0x4E, rot3=[3,0,1,2]=0x93

__device__ __forceinline__ float fast_tanh(float a) {
    // tanh(a) = (e-1)/(e+1), e = 2^(a*2/ln2). Upper clamp only: for very
    // negative a, exp2 -> 0 and the formula gives -1 exactly.
#if __has_builtin(__builtin_amdgcn_exp2f)
    float m = fminf(a * 2.885390081777927f, 126.0f);
    float e = __builtin_amdgcn_exp2f(m);
#else
    float m = fminf(a * 2.885390081777927f, 126.0f);
    float e = exp2f(m);
#endif
#if __has_builtin(__builtin_amdgcn_rcpf)
    return (e - 1.0f) * __builtin_amdgcn_rcpf(e + 1.0f);
#else
    return (e - 1.0f) / (e + 1.0f);
#endif
}

#define STEP(xx, yy, toff) do { \
    float p1x = QROT(h0, 0x39), p1y = QROT(h1, 0x39); \
    float p2x = QROT(h0, 0x4E), p2y = QROT(h1, 0x4E); \
    float p3x = QROT(h0, 0x93), p3y = QROT(h1, 0x93); \
    float a0 = fmaf(h0, w0[0], (xx)); \
    float a1 = fmaf(h0, w1[0], (yy)); \
    a0 = fmaf(h1,  w0[1], a0); a1 = fmaf(h1,  w1[1], a1); \
    a0 = fmaf(p1x, w0[2], a0); a1 = fmaf(p1x, w1[2], a1); \
    a0 = fmaf(p1y, w0[3], a0); a1 = fmaf(p1y, w1[3], a1); \
    a0 = fmaf(p2x, w0[4], a0); a1 = fmaf(p2x, w1[4], a1); \
    a0 = fmaf(p2y, w0[5], a0); a1 = fmaf(p2y, w1[5], a1); \
    a0 = fmaf(p3x, w0[6], a0); a1 = fmaf(p3x, w1[6], a1); \
    a0 = fmaf(p3y, w0[7], a0); a1 = fmaf(p3y, w1[7], a1); \
    h0 = fast_tanh(a0); h1 = fast_tanh(a1); \
    *(float2*)(hs_base + (size_t)(toff) * 8) = make_float2(h0, h1); \
} while (0)

__global__ __launch_bounds__(64) void k_scan(
    const float* __restrict__ xpT, const float* __restrict__ W_hh,
    float* __restrict__ hs)
{
    int lane = threadIdx.x;                 // 0..63, one wave
    int b = blockIdx.x * 16 + (lane >> 2);  // 16 batches per wave
    int q = lane & 3;
    int i0 = 2 * q, i1 = 2 * q + 1;

    // Weights in quad-rotation order: term r uses h-pair from lane (q+r)&3.
    float w0[8], w1[8];
#pragma unroll
    for (int r = 0; r < 4; ++r) {
        int jj = ((q + r) & 3) * 2;
        w0[2 * r]     = W_hh[i0 * 8 + jj];
        w0[2 * r + 1] = W_hh[i0 * 8 + jj + 1];
        w1[2 * r]     = W_hh[i1 * 8 + jj];
        w1[2 * r + 1] = W_hh[i1 * 8 + jj + 1];
    }

    const float4* xp4 = (const float4*)(xpT + (size_t)(b * 4 + q) * Tz * 2);
    float* hs_base = hs + (size_t)b * Tz * 8 + 2 * q;

    float h0 = 0.0f, h1 = 0.0f;
    float4 c0 = xp4[0], c1 = xp4[1], c2 = xp4[2], c3 = xp4[3];

    for (int c = 0; c < Tz / 8; ++c) {
        // prefetch next chunk (reads 64B past the end on the last iteration,
        // which lands in the hs region of the workspace -- harmless)
        float4 n0 = xp4[4 * c + 4], n1 = xp4[4 * c + 5];
        float4 n2 = xp4[4 * c + 6], n3 = xp4[4 * c + 7];
        int t0 = c * 8;
        STEP(c0.x, c0.y, t0 + 0); STEP(c0.z, c0.w, t0 + 1);
        STEP(c1.x, c1.y, t0 + 2); STEP(c1.z, c1.w, t0 + 3);
        STEP(c2.x, c2.y, t0 + 4); STEP(c2.z, c2.w, t0 + 5);
        STEP(c3.x, c3.y, t0 + 6); STEP(c3.z, c3.w, t0 + 7);
        c0 = n0; c1 = n1; c2 = n2; c3 = n3;
    }
}

// ---------------------------------------------------------------------------
// Kernel 3: logits[r, o] = sum_i hs_masked[r,i] * W_out[o,i] + b_out[o]
// Length mask applied during LDS staging. Nontemporal float4 stores for the
// 524 MB logits stream (avoid L2 write-allocate fills).
// ---------------------------------------------------------------------------
__global__ __launch_bounds__(256) void k_out(
    const float* __restrict__ hs, const int* __restrict__ lengths,
    const float* __restrict__ W_out, const float* __restrict__ b_out,
    float* __restrict__ out)
{
    __shared__ float4 sh4[256];  // 128 rows x 8 floats
    int tid = threadIdx.x;
    int r0 = blockIdx.x * 128;

    // cooperative stage of 128 hs rows, applying the length mask
    {
        int row = r0 + (tid >> 1);
        int b = row >> 11, t = row & 2047;
        float4 v = ((const float4*)hs)[(size_t)r0 * 2 + tid];
        if (t >= lengths[b]) v = make_float4(0.f, 0.f, 0.f, 0.f);
        sh4[tid] = v;
    }
    __syncthreads();

    if (tid >= Oz / 4) return;  // 250 active threads

    float w[4][8];
    float bo[4];
#pragma unroll
    for (int k = 0; k < 4; ++k) {
        const float4* wr = (const float4*)(W_out + (size_t)(tid * 4 + k) * 8);
        float4 wa = wr[0], wb = wr[1];
        w[k][0] = wa.x; w[k][1] = wa.y; w[k][2] = wa.z; w[k][3] = wa.w;
        w[k][4] = wb.x; w[k][5] = wb.y; w[k][6] = wb.z; w[k][7] = wb.w;
        bo[k] = b_out[tid * 4 + k];
    }

    for (int rr = 0; rr < 128; ++rr) {
        float4 ha = sh4[rr * 2], hb = sh4[rr * 2 + 1];  // LDS broadcast reads
        float r[4];
#pragma unroll
        for (int k = 0; k < 4; ++k) {
            float a = bo[k];
            a = fmaf(ha.x, w[k][0], a); a = fmaf(ha.y, w[k][1], a);
            a = fmaf(ha.z, w[k][2], a); a = fmaf(ha.w, w[k][3], a);
            a = fmaf(hb.x, w[k][4], a); a = fmaf(hb.y, w[k][5], a);
            a = fmaf(hb.z, w[k][6], a); a = fmaf(hb.w, w[k][7], a);
            r[k] = a;
        }
        f32x4 acc = { r[0], r[1], r[2], r[3] };
        __builtin_nontemporal_store(
            acc, (f32x4*)(out + (size_t)(r0 + rr) * Oz) + tid);
    }
}

// ---------------------------------------------------------------------------
extern "C" void kernel_launch(void* const* d_in, const int* in_sizes, int n_in,
                              void* d_out, int out_size, void* d_ws, size_t ws_size,
                              hipStream_t stream)
{
    const int*   X       = (const int*)d_in[0];
    const int*   lengths = (const int*)d_in[1];
    const float* emb     = (const float*)d_in[2];
    const float* W_ih    = (const float*)d_in[3];
    const float* W_hh    = (const float*)d_in[4];
    const float* b_ih    = (const float*)d_in[5];
    const float* b_hh    = (const float*)d_in[6];
    const float* W_out   = (const float*)d_in[7];
    const float* b_out   = (const float*)d_in[8];

    float* out   = (float*)d_out;
    float* xpT   = (float*)d_ws;                     // 4 MB (lane-major x_proj)
    float* hs    = xpT + (size_t)Bz * Tz * Hz;       // 4 MB (needs ws >= 8 MB)

    // lengths tail of d_out (output 1 of the tuple)
    float* out_tail = out + (size_t)Bz * Tz * Oz;

    k_xproj<<<(Bz * Tz + 255) / 256, 256, 0, stream>>>(X, lengths, emb, W_ih,
                                                       b_ih, b_hh, xpT, out_tail);
    k_scan<<<Bz / 16, 64, 0, stream>>>(xpT, W_hh, hs);
    k_out<<<(Bz * Tz) / 128, 256, 0, stream>>>(hs, lengths, W_out, b_out, out);
}